// Round 8
// baseline (1531.953 us; speedup 1.0000x reference)
//
#include <hip/hip_runtime.h>
#include <hip/hip_bf16.h>
#include <hip/hip_cooperative_groups.h>

namespace cg = cooperative_groups;

// ---------------------------------------------------------------------------
// Sparse conv backbone, bf16 MFMA, round 18 = cooperative mega-kernel + safe
// fallback. r16/r17's custom spin barrier hung the container (co-residency
// assumption had no safety net). r18 uses the blessed path:
//   * hipLaunchCooperativeKernel + cg::this_grid().sync() — launch FAILS
//     (returns error) instead of deadlocking if the grid can't co-reside.
//   * on ANY launch error -> fallback to the proven r13-style multi-kernel
//     sequence built from the same stage device-functions (thin wrappers).
// Stage bodies identical to r10/r17 (numerics: absmax 0.109).
// ---------------------------------------------------------------------------

typedef float f4 __attribute__((ext_vector_type(4)));
typedef short short8 __attribute__((ext_vector_type(8)));
typedef short short4v __attribute__((ext_vector_type(4)));

#define BN_EPS 1e-5f

static inline int ceil_div(int a, int b) { return (a + b - 1) / b; }

static __device__ inline float btof(short s) {
    unsigned u = ((unsigned)(unsigned short)s) << 16;
    float f;
    __builtin_memcpy(&f, &u, 4);
    return f;
}
static __device__ inline short ftob(float f) {
    __hip_bfloat16 h = __float2bfloat16(f);
    short s;
    __builtin_memcpy(&s, &h, 2);
    return s;
}

struct Seg {
    const float* W;
    long long begin, end;
    int K, CIN, COUT;
};

struct MegaArgs {
    Seg s[10];
    const float* geo;
    const float* col;
    __hip_bfloat16* x0;
    int n_vox;
    float* stats;
    __hip_bfloat16* pads[5];
    int padn[5];
    long long wf_total;
    long long pro_total;
    __hip_bfloat16* Wf;
    const int *m1, *m2, *m3, *m4;
    __hip_bfloat16 *A, *B, *Cb, *D, *E, *Fb;
    float* out_f32;
    int nc2, nc4;
    long long off_e1[4], off_c2, off_e2[4];
    const float *g_e1, *b_e1, *g_e2, *b_e2;
};

// ---------------- BN coefficient helper ----------------
template <int C>
__device__ inline void bn_coef(const float* st, const float* g, const float* b,
                               int c, int n, float& sc, float& sh) {
    float rn = 1.f / (float)n;
    float sum = st[c] + st[2 * C + c] + st[4 * C + c] + st[6 * C + c];
    float sq  = st[C + c] + st[3 * C + c] + st[5 * C + c] + st[7 * C + c];
    float mu = sum * rn;
    float inv = rsqrtf(sq * rn - mu * mu + BN_EPS);
    sc = inv * g[c];
    sh = b[c] - mu * sc;
}

// ---------------- stage: prologue (weights pack + x0 + zero stats/pads) -----
__device__ void prologue_stage(const MegaArgs& pa) {
    for (long long e = (long long)blockIdx.x * 256 + threadIdx.x; e < pa.pro_total;
         e += (long long)gridDim.x * 256) {
        if (e < pa.wf_total) {
            int si = 0;
#pragma unroll
            for (int i = 0; i < 10; ++i)
                if (e >= pa.s[i].end) si = i + 1;
            const Seg sg = pa.s[si];
            long long r = e - sg.begin;
            int j = (int)(r & 7);
            int lane = (int)((r >> 3) & 63);
            long long rest = r >> 9;
            int NT = sg.COUT >> 4;
            int ntile = (int)(rest % NT);
            int chunk = (int)(rest / NT);
            int kd = chunk * 32 + ((lane >> 4) << 3) + j;
            int koff = kd / sg.CIN;
            int ci = kd % sg.CIN;
            int n = ntile * 16 + (lane & 15);
            float v = (koff < sg.K) ? sg.W[((size_t)koff * sg.CIN + ci) * sg.COUT + n] : 0.f;
            pa.Wf[e] = __float2bfloat16(v);
            continue;
        }
        long long r = e - pa.wf_total;
        if (r < pa.n_vox) {
            int row = (int)r;
            pa.x0[row * 4 + 0] = __float2bfloat16(pa.geo[row]);
            pa.x0[row * 4 + 1] = __float2bfloat16(pa.col[row * 3 + 0]);
            pa.x0[row * 4 + 2] = __float2bfloat16(pa.col[row * 3 + 1]);
            pa.x0[row * 4 + 3] = __float2bfloat16(pa.col[row * 3 + 2]);
            continue;
        }
        r -= pa.n_vox;
        if (r < 4096) {
            pa.stats[r] = 0.f;
            continue;
        }
        r -= 4096;
#pragma unroll
        for (int i = 0; i < 5; ++i) {
            if (r < pa.padn[i]) {
                pa.pads[i][r] = __float2bfloat16(0.f);
                r = -1;
                break;
            }
            r -= pa.padn[i];
        }
    }
}

// ---------------- stage: stem conv (CIN=4, COUT=32, K=125->128, relu) -------
__device__ void stem_stage(const MegaArgs& a) {
    const int t = threadIdx.x, w = t >> 6, lane = t & 63;
    const int quad = lane >> 4, ml = lane & 15;
    const int ntile = w & 1, mgroup = w >> 1;
    const int n_out = a.nc2, n_in = a.n_vox;
    const __hip_bfloat16* feat = a.x0;
    const __hip_bfloat16* Wf = a.Wf;   // stem at offset 0
    const int* in_map = a.m1;
    __hip_bfloat16* out = a.A;
    const int nblk = (n_out + 63) / 64;
    for (int b = (int)blockIdx.x; b < nblk; b += (int)gridDim.x) {
        const int mb = b * 64 + mgroup * 32;
        const int m0 = mb + ml, m1 = mb + 16 + ml;
        const bool v0 = m0 < n_out, v1 = m1 < n_out;
        f4 acc0 = {0.f, 0.f, 0.f, 0.f};
        f4 acc1 = {0.f, 0.f, 0.f, 0.f};
#pragma unroll 2
        for (int chunk = 0; chunk < 16; ++chunk) {
            int k0 = chunk * 8 + quad * 2;
            int k1 = k0 + 1;
            int k0c = (k0 < 125) ? k0 : 0;
            int k1c = (k1 < 125) ? k1 : 0;
            short8 bw = *(const short8*)(Wf + ((size_t)(chunk * 2 + ntile) * 64 + lane) * 8);
            int ia = v0 ? in_map[(size_t)k0c * n_out + m0] : n_in;
            int ib = v0 ? in_map[(size_t)k1c * n_out + m0] : n_in;
            int ic = v1 ? in_map[(size_t)k0c * n_out + m1] : n_in;
            int id = v1 ? in_map[(size_t)k1c * n_out + m1] : n_in;
            short4v p0 = *(const short4v*)(feat + (size_t)ia * 4);
            short4v p1 = *(const short4v*)(feat + (size_t)ib * 4);
            short4v p2 = *(const short4v*)(feat + (size_t)ic * 4);
            short4v p3 = *(const short4v*)(feat + (size_t)id * 4);
            short8 a0, a1;
            a0[0] = p0[0]; a0[1] = p0[1]; a0[2] = p0[2]; a0[3] = p0[3];
            a0[4] = p1[0]; a0[5] = p1[1]; a0[6] = p1[2]; a0[7] = p1[3];
            a1[0] = p2[0]; a1[1] = p2[1]; a1[2] = p2[2]; a1[3] = p2[3];
            a1[4] = p3[0]; a1[5] = p3[1]; a1[6] = p3[2]; a1[7] = p3[3];
            acc0 = __builtin_amdgcn_mfma_f32_16x16x32_bf16(a0, bw, acc0, 0, 0, 0);
            acc1 = __builtin_amdgcn_mfma_f32_16x16x32_bf16(a1, bw, acc1, 0, 0, 0);
        }
        const int col = ntile * 16 + ml;
#pragma unroll
        for (int i = 0; i < 4; ++i) {
            int r0 = mb + quad * 4 + i;
            if (r0 < n_out)
                out[(size_t)r0 * 32 + col] = __float2bfloat16(fmaxf(acc0[i], 0.f));
            int r1 = mb + 16 + quad * 4 + i;
            if (r1 < n_out)
                out[(size_t)r1 * 32 + col] = __float2bfloat16(fmaxf(acc1[i], 0.f));
        }
    }
}

// ---------------- stage: split-K MFMA conv (r10 body, block-stride) ---------
template <int CIN, int COUT, int MT, int K, bool BNF>
__device__ void conv_stage(float* red, float* sred, float* ibn,
                           const __hip_bfloat16* feat, const __hip_bfloat16* Wf,
                           const int* in_map, __hip_bfloat16* out, float* stats,
                           const float* in_stats, const float* in_g,
                           const float* in_b, int n_out, int n_in) {
    constexpr int NT = COUT / 16;
    constexpr int H = CIN / 32;
    constexpr int R = MT * 16;
    constexpr int KPW = (K + 3) / 4;
    constexpr int SP = COUT + 1;
    const int t = threadIdx.x, w = t >> 6, lane = t & 63;
    const int quad = lane >> 4, ml = lane & 15;
    const int nblk = (n_out + R - 1) / R;

    if constexpr (BNF) {
        if (t < CIN) {
            float sc, sh;
            bn_coef<CIN>(in_stats, in_g, in_b, t, n_in, sc, sh);
            ibn[t] = sc;
            ibn[CIN + t] = sh;
        }
        __syncthreads();
    }
    float scr[H][8], shr[H][8];
    if constexpr (BNF) {
#pragma unroll
        for (int h = 0; h < H; ++h)
#pragma unroll
            for (int j = 0; j < 8; ++j) {
                int ch = h * 32 + quad * 8 + j;
                scr[h][j] = ibn[ch];
                shr[h][j] = ibn[CIN + ch];
            }
    }

    for (int b = (int)blockIdx.x; b < nblk; b += (int)gridDim.x) {
        const int mb = b * R;
        f4 acc[MT * NT];
#pragma unroll
        for (int i = 0; i < MT * NT; ++i) acc[i] = (f4){0.f, 0.f, 0.f, 0.f};

#pragma unroll
        for (int kk = 0; kk < KPW; ++kk) {
            const int k = kk * 4 + w;
            const int krow = (k < K) ? k : 0;
            const int* mk = in_map + (size_t)krow * n_out;
            int idx[MT];
#pragma unroll
            for (int mi = 0; mi < MT; ++mi) {
                int m = mb + mi * 16 + ml;
                idx[mi] = (m < n_out) ? mk[m] : n_in;
            }
            short8 bfrag[H * NT];
#pragma unroll
            for (int h = 0; h < H; ++h)
#pragma unroll
                for (int nt = 0; nt < NT; ++nt)
                    bfrag[h * NT + nt] = *(const short8*)(
                        Wf + (((size_t)(k * H + h) * NT + nt) * 64 + lane) * 8);
#pragma unroll
            for (int mi = 0; mi < MT; ++mi) {
                const __hip_bfloat16* fp = feat + (size_t)idx[mi] * CIN + quad * 8;
                const bool sent = (idx[mi] == n_in);
#pragma unroll
                for (int h = 0; h < H; ++h) {
                    short8 av = *(const short8*)(fp + h * 32);
                    if constexpr (BNF) {
#pragma unroll
                        for (int j = 0; j < 8; ++j) {
                            float f = btof(av[j]) * scr[h][j] + shr[h][j];
                            f = fmaxf(f, 0.f);
                            av[j] = sent ? (short)0 : ftob(f);
                        }
                    }
#pragma unroll
                    for (int nt = 0; nt < NT; ++nt)
                        acc[mi * NT + nt] = __builtin_amdgcn_mfma_f32_16x16x32_bf16(
                            av, bfrag[h * NT + nt], acc[mi * NT + nt], 0, 0, 0);
                }
            }
        }

#pragma unroll
        for (int mi = 0; mi < MT; ++mi)
#pragma unroll
            for (int nt = 0; nt < NT; ++nt)
#pragma unroll
                for (int i = 0; i < 4; ++i)
                    red[((size_t)w * R + mi * 16 + quad * 4 + i) * SP + nt * 16 + ml] =
                        acc[mi * NT + nt][i];
        __syncthreads();

        constexpr int E = (R * COUT) / 256;
        constexpr int RSTEP = 256 / COUT;
        const int col = t % COUT;
        const int rg = t / COUT;
        float s = 0.f, s2 = 0.f;
#pragma unroll
        for (int i = 0; i < E; ++i) {
            int r = rg + i * RSTEP;
            float v = red[(0 * R + r) * SP + col] + red[(1 * R + r) * SP + col] +
                      red[(2 * R + r) * SP + col] + red[(3 * R + r) * SP + col];
            s += v;
            s2 += v * v;
            int grow = mb + r;
            if (grow < n_out) out[(size_t)grow * COUT + col] = __float2bfloat16(v);
        }

        if (stats) {
            sred[t] = s;
            sred[256 + t] = s2;
            __syncthreads();
            if (t < 2 * COUT) {
                int c = t % COUT;
                int which = t / COUT;
                float v = 0.f;
#pragma unroll
                for (int j = 0; j < RSTEP; ++j) v += sred[which * 256 + j * COUT + c];
                atomicAdd(&stats[((b & 3) * 2 + which) * COUT + c], v);
            }
        }
        __syncthreads();   // protect red/sred reuse on next stride iteration
    }
}

// ---------------- stage: BN (+residual) apply ----------------
template <int C, bool F32OUT>
__device__ void bnres_stage(float* ibn, const __hip_bfloat16* y,
                            const __hip_bfloat16* res, const float* st,
                            const float* g, const float* b, void* outp, int n) {
    const int t = threadIdx.x;
    if (t < C) {
        float sc, sh;
        bn_coef<C>(st, g, b, t, n, sc, sh);
        ibn[t] = sc;
        ibn[C + t] = sh;
    }
    __syncthreads();
    long long tot = (long long)n * (C / 8);
    for (long long i = (long long)blockIdx.x * 256 + t; i < tot;
         i += (long long)gridDim.x * 256) {
        int c0 = (int)(i % (C / 8)) * 8;
        short8 v = *(const short8*)(y + i * 8);
        short8 r = *(const short8*)(res + i * 8);
        if constexpr (F32OUT) {
            float* out = (float*)outp;
            f4 o0, o1;
#pragma unroll
            for (int j = 0; j < 8; ++j) {
                float f = btof(v[j]) * ibn[c0 + j] + ibn[C + c0 + j] + btof(r[j]);
                f = fmaxf(f, 0.f);
                if (j < 4) o0[j] = f; else o1[j - 4] = f;
            }
            *(f4*)(out + i * 8) = o0;
            *(f4*)(out + i * 8 + 4) = o1;
        } else {
            __hip_bfloat16* out = (__hip_bfloat16*)outp;
            short8 o;
#pragma unroll
            for (int j = 0; j < 8; ++j) {
                float f = btof(v[j]) * ibn[c0 + j] + ibn[C + c0 + j] + btof(r[j]);
                o[j] = ftob(fmaxf(f, 0.f));
            }
            *(short8*)(out + i * 8) = o;
        }
    }
    __syncthreads();   // ibn reuse safety across stages
}

// ---------------- the cooperative mega kernel ----------------
__global__ __launch_bounds__(256, 4) void k_mega(MegaArgs a) {
    cg::grid_group grid = cg::this_grid();
    __shared__ float smem[9088];       // red 8448 | sred 512 | ibn 128 floats
    float* red = smem;
    float* sred = smem + 8448;
    float* ibn = smem + 8960;

    prologue_stage(a);
    grid.sync();
    stem_stage(a);
    grid.sync();

    conv_stage<32, 32, 4, 27, false>(red, sred, ibn, a.A, a.Wf + a.off_e1[0], a.m2,
                                     a.B, a.stats + 0 * 512,
                                     nullptr, nullptr, nullptr, a.nc2, a.nc2);
    grid.sync();
    conv_stage<32, 32, 4, 27, true>(red, sred, ibn, a.B, a.Wf + a.off_e1[1], a.m2,
                                    a.Cb, a.stats + 1 * 512,
                                    a.stats + 0 * 512, a.g_e1 + 0, a.b_e1 + 0,
                                    a.nc2, a.nc2);
    grid.sync();
    bnres_stage<32, false>(ibn, a.Cb, a.A, a.stats + 1 * 512, a.g_e1 + 32,
                           a.b_e1 + 32, a.A, a.nc2);
    grid.sync();

    conv_stage<32, 32, 4, 27, false>(red, sred, ibn, a.A, a.Wf + a.off_e1[2], a.m2,
                                     a.B, a.stats + 2 * 512,
                                     nullptr, nullptr, nullptr, a.nc2, a.nc2);
    grid.sync();
    conv_stage<32, 32, 4, 27, true>(red, sred, ibn, a.B, a.Wf + a.off_e1[3], a.m2,
                                    a.Cb, a.stats + 3 * 512,
                                    a.stats + 2 * 512, a.g_e1 + 64, a.b_e1 + 64,
                                    a.nc2, a.nc2);
    grid.sync();
    bnres_stage<32, false>(ibn, a.Cb, a.A, a.stats + 3 * 512, a.g_e1 + 96,
                           a.b_e1 + 96, a.A, a.nc2);
    grid.sync();

    conv_stage<32, 64, 1, 27, false>(red, sred, ibn, a.A, a.Wf + a.off_c2, a.m3,
                                     a.D, nullptr,
                                     nullptr, nullptr, nullptr, a.nc4, a.nc2);
    grid.sync();

    conv_stage<64, 64, 1, 27, false>(red, sred, ibn, a.D, a.Wf + a.off_e2[0], a.m4,
                                     a.E, a.stats + 4 * 512,
                                     nullptr, nullptr, nullptr, a.nc4, a.nc4);
    grid.sync();
    conv_stage<64, 64, 1, 27, true>(red, sred, ibn, a.E, a.Wf + a.off_e2[1], a.m4,
                                    a.Fb, a.stats + 5 * 512,
                                    a.stats + 4 * 512, a.g_e2 + 0, a.b_e2 + 0,
                                    a.nc4, a.nc4);
    grid.sync();
    bnres_stage<64, false>(ibn, a.Fb, a.D, a.stats + 5 * 512, a.g_e2 + 64,
                           a.b_e2 + 64, a.D, a.nc4);
    grid.sync();

    conv_stage<64, 64, 1, 27, false>(red, sred, ibn, a.D, a.Wf + a.off_e2[2], a.m4,
                                     a.E, a.stats + 6 * 512,
                                     nullptr, nullptr, nullptr, a.nc4, a.nc4);
    grid.sync();
    conv_stage<64, 64, 1, 27, true>(red, sred, ibn, a.E, a.Wf + a.off_e2[3], a.m4,
                                    a.Fb, a.stats + 7 * 512,
                                    a.stats + 6 * 512, a.g_e2 + 128, a.b_e2 + 128,
                                    a.nc4, a.nc4);
    grid.sync();
    bnres_stage<64, true>(ibn, a.Fb, a.D, a.stats + 7 * 512, a.g_e2 + 192,
                          a.b_e2 + 192, a.out_f32, a.nc4);
}

// ---------------- fallback wrapper kernels (multi-launch path) --------------
__global__ __launch_bounds__(256) void k_pro_g(MegaArgs a) { prologue_stage(a); }
__global__ __launch_bounds__(256) void k_stem_g(MegaArgs a) { stem_stage(a); }

template <int CIN, int COUT, int MT, int K, bool BNF>
__global__ __launch_bounds__(256, 4) void k_conv_g(
    const __hip_bfloat16* __restrict__ feat, const __hip_bfloat16* __restrict__ Wf,
    const int* __restrict__ in_map, __hip_bfloat16* __restrict__ out,
    float* __restrict__ stats, const float* __restrict__ in_stats,
    const float* __restrict__ in_g, const float* __restrict__ in_b,
    int n_out, int n_in) {
    __shared__ float smem[9088];
    conv_stage<CIN, COUT, MT, K, BNF>(smem, smem + 8448, smem + 8960, feat, Wf,
                                      in_map, out, stats, in_stats, in_g, in_b,
                                      n_out, n_in);
}

template <int C, bool F32OUT>
__global__ __launch_bounds__(256) void k_bnres_g(
    const __hip_bfloat16* __restrict__ y, const __hip_bfloat16* __restrict__ res,
    const float* __restrict__ st, const float* __restrict__ g,
    const float* __restrict__ b, void* outp, int n) {
    __shared__ float ibn[2 * C];
    bnres_stage<C, F32OUT>(ibn, y, res, st, g, b, outp, n);
}

// ---------------------------------------------------------------------------
extern "C" void kernel_launch(void* const* d_in, const int* in_sizes, int n_in_cnt,
                              void* d_out, int out_size, void* d_ws, size_t ws_size,
                              hipStream_t stream) {
    const float* x_geo = (const float*)d_in[0];
    const float* x_col = (const float*)d_in[1];
    const float* w0    = (const float*)d_in[2];
    const float* w_e1  = (const float*)d_in[3];
    const float* g_e1  = (const float*)d_in[4];
    const float* b_e1  = (const float*)d_in[5];
    const float* w2    = (const float*)d_in[6];
    const float* w_e2  = (const float*)d_in[7];
    const float* g_e2  = (const float*)d_in[8];
    const float* b_e2  = (const float*)d_in[9];
    const int* m1 = (const int*)d_in[10];
    const int* m2 = (const int*)d_in[12];
    const int* m3 = (const int*)d_in[14];
    const int* m4 = (const int*)d_in[16];

    const int n_vox = in_sizes[0];
    const int nc2 = in_sizes[10] / 125;
    const int nc4 = in_sizes[14] / 27;
    (void)out_size; (void)ws_size; (void)n_in_cnt;

    char* p = (char*)d_ws;
    auto alloc = [&](size_t bytes) -> char* {
        char* r = p;
        p += (bytes + 255) & ~(size_t)255;
        return r;
    };
    float* stats = (float*)alloc(8 * 512 * sizeof(float));
    __hip_bfloat16* x0 = (__hip_bfloat16*)alloc((size_t)(n_vox + 1) * 4 * 2);
    __hip_bfloat16* A  = (__hip_bfloat16*)alloc((size_t)(nc2 + 1) * 32 * 2);
    __hip_bfloat16* B  = (__hip_bfloat16*)alloc((size_t)(nc2 + 1) * 32 * 2);
    __hip_bfloat16* Cb = (__hip_bfloat16*)alloc((size_t)(nc2 + 1) * 32 * 2);
    __hip_bfloat16* D  = (__hip_bfloat16*)alloc((size_t)(nc4 + 1) * 64 * 2);
    __hip_bfloat16* E  = (__hip_bfloat16*)alloc((size_t)(nc4 + 1) * 64 * 2);
    __hip_bfloat16* Fb = (__hip_bfloat16*)alloc((size_t)(nc4 + 1) * 64 * 2);

    const long long sz_stem = 16LL * 2 * 512;
    const long long sz_e1   = 28LL * 2 * 512;
    const long long sz_c2   = 28LL * 4 * 512;
    const long long sz_e2   = 56LL * 4 * 512;
    const long long wf_total = sz_stem + 4 * sz_e1 + sz_c2 + 4 * sz_e2;
    __hip_bfloat16* Wf = (__hip_bfloat16*)alloc((size_t)wf_total * 2);

    MegaArgs ma;
    long long cur = 0;
    auto seg = [&](int i, const float* W, int K, int CIN, int COUT, long long n) {
        ma.s[i].W = W; ma.s[i].K = K; ma.s[i].CIN = CIN; ma.s[i].COUT = COUT;
        ma.s[i].begin = cur; ma.s[i].end = cur + n; cur += n;
    };
    seg(0, w0, 125, 4, 32, sz_stem);
    for (int i = 0; i < 4; ++i)
        seg(1 + i, w_e1 + (size_t)i * 27 * 32 * 32, 27, 32, 32, sz_e1);
    seg(5, w2, 27, 32, 64, sz_c2);
    for (int i = 0; i < 4; ++i)
        seg(6 + i, w_e2 + (size_t)i * 27 * 64 * 64, 27, 64, 64, sz_e2);

    cur = sz_stem;
    for (int i = 0; i < 4; ++i) { ma.off_e1[i] = cur; cur += sz_e1; }
    ma.off_c2 = cur; cur += sz_c2;
    for (int i = 0; i < 4; ++i) { ma.off_e2[i] = cur; cur += sz_e2; }

    ma.geo = x_geo; ma.col = x_col; ma.x0 = x0; ma.n_vox = n_vox;
    ma.stats = stats;
    ma.pads[0] = x0 + (size_t)n_vox * 4; ma.padn[0] = 4;
    ma.pads[1] = A + (size_t)nc2 * 32;   ma.padn[1] = 32;
    ma.pads[2] = B + (size_t)nc2 * 32;   ma.padn[2] = 32;
    ma.pads[3] = D + (size_t)nc4 * 64;   ma.padn[3] = 64;
    ma.pads[4] = E + (size_t)nc4 * 64;   ma.padn[4] = 64;
    ma.wf_total = wf_total;
    ma.pro_total = wf_total + n_vox + 4096 + (4 + 32 + 32 + 64 + 64);
    ma.Wf = Wf;
    ma.m1 = m1; ma.m2 = m2; ma.m3 = m3; ma.m4 = m4;
    ma.A = A; ma.B = B; ma.Cb = Cb; ma.D = D; ma.E = E; ma.Fb = Fb;
    ma.out_f32 = (float*)d_out;
    ma.nc2 = nc2; ma.nc4 = nc4;
    ma.g_e1 = g_e1; ma.b_e1 = b_e1; ma.g_e2 = g_e2; ma.b_e2 = b_e2;

    // ---- cooperative grid sizing (validated by the runtime at launch) ----
    static int nb_cached = -1;
    if (nb_cached < 0) {
        int per_cu = 0;
        if (hipOccupancyMaxActiveBlocksPerMultiprocessor(&per_cu, k_mega, 256, 0)
                != hipSuccess || per_cu < 1)
            per_cu = 1;
        int ncu = 0;
        if (hipDeviceGetAttribute(&ncu, hipDeviceAttributeMultiprocessorCount, 0)
                != hipSuccess || ncu < 1)
            ncu = 256;
        long long cap = (long long)per_cu * ncu;
        if (cap > 2048) cap = 2048;
        if (cap < 1) cap = 1;
        nb_cached = (int)cap;
    }

    void* kargs[] = { (void*)&ma };
    hipError_t ce = hipLaunchCooperativeKernel(
        reinterpret_cast<void*>(k_mega), dim3(nb_cached), dim3(256),
        kargs, 0, stream);

    if (ce != hipSuccess) {
        // ---- fallback: proven multi-kernel sequence (r13-equivalent) ----
        k_pro_g<<<ceil_div((int)ma.pro_total, 256), 256, 0, stream>>>(ma);
        k_stem_g<<<ceil_div(nc2, 64), 256, 0, stream>>>(ma);

        k_conv_g<32, 32, 4, 27, false><<<ceil_div(nc2, 64), 256, 0, stream>>>(
            A, Wf + ma.off_e1[0], m2, B, stats + 0 * 512,
            nullptr, nullptr, nullptr, nc2, nc2);
        k_conv_g<32, 32, 4, 27, true><<<ceil_div(nc2, 64), 256, 0, stream>>>(
            B, Wf + ma.off_e1[1], m2, Cb, stats + 1 * 512,
            stats + 0 * 512, g_e1 + 0, b_e1 + 0, nc2, nc2);
        k_bnres_g<32, false><<<ceil_div(nc2 * 4, 256), 256, 0, stream>>>(
            Cb, A, stats + 1 * 512, g_e1 + 32, b_e1 + 32, A, nc2);

        k_conv_g<32, 32, 4, 27, false><<<ceil_div(nc2, 64), 256, 0, stream>>>(
            A, Wf + ma.off_e1[2], m2, B, stats + 2 * 512,
            nullptr, nullptr, nullptr, nc2, nc2);
        k_conv_g<32, 32, 4, 27, true><<<ceil_div(nc2, 64), 256, 0, stream>>>(
            B, Wf + ma.off_e1[3], m2, Cb, stats + 3 * 512,
            stats + 2 * 512, g_e1 + 64, b_e1 + 64, nc2, nc2);
        k_bnres_g<32, false><<<ceil_div(nc2 * 4, 256), 256, 0, stream>>>(
            Cb, A, stats + 3 * 512, g_e1 + 96, b_e1 + 96, A, nc2);

        k_conv_g<32, 64, 1, 27, false><<<ceil_div(nc4, 16), 256, 0, stream>>>(
            A, Wf + ma.off_c2, m3, D, nullptr,
            nullptr, nullptr, nullptr, nc4, nc2);

        k_conv_g<64, 64, 1, 27, false><<<ceil_div(nc4, 16), 256, 0, stream>>>(
            D, Wf + ma.off_e2[0], m4, E, stats + 4 * 512,
            nullptr, nullptr, nullptr, nc4, nc4);
        k_conv_g<64, 64, 1, 27, true><<<ceil_div(nc4, 16), 256, 0, stream>>>(
            E, Wf + ma.off_e2[1], m4, Fb, stats + 5 * 512,
            stats + 4 * 512, g_e2 + 0, b_e2 + 0, nc4, nc4);
        k_bnres_g<64, false><<<ceil_div(nc4 * 8, 256), 256, 0, stream>>>(
            Fb, D, stats + 5 * 512, g_e2 + 64, b_e2 + 64, D, nc4);

        k_conv_g<64, 64, 1, 27, false><<<ceil_div(nc4, 16), 256, 0, stream>>>(
            D, Wf + ma.off_e2[2], m4, E, stats + 6 * 512,
            nullptr, nullptr, nullptr, nc4, nc4);
        k_conv_g<64, 64, 1, 27, true><<<ceil_div(nc4, 16), 256, 0, stream>>>(
            E, Wf + ma.off_e2[3], m4, Fb, stats + 7 * 512,
            stats + 6 * 512, g_e2 + 128, b_e2 + 128, nc4, nc4);
        k_bnres_g<64, true><<<ceil_div(nc4 * 8, 256), 256, 0, stream>>>(
            Fb, D, stats + 7 * 512, g_e2 + 192, b_e2 + 192, (float*)d_out, nc4);
    }
}

// Round 9
// 323.141 us; speedup vs baseline: 4.7408x; 4.7408x over previous
//
#include <hip/hip_runtime.h>
#include <hip/hip_bf16.h>

// ---------------------------------------------------------------------------
// Sparse conv backbone, bf16 MFMA, round 19 = r14 + async LDS-staged gathers.
// r18 mega-kernel verdict: grid.sync costs ~100us each + L2 flush (1.56 GB
// HBM traffic, 2226us) -> kernel boundaries are CHEAP; the convs themselves
// are gather-latency-bound. Chain model: concurrent gather chains/SIMD =
// n_rows/4/1024 (invariant to MT under split-K4): enc1 14 -> 21us, enc2 3.4
// -> 23us, r12 split-M 3.5 -> 46us (all fit). Register prefetch was sunk by
// the compiler (r14 VGPR=36). Fix the compiler can't undo:
//   * __builtin_amdgcn_global_load_lds(16B) async gathers, depth-D pipeline
//     (D=4 for MT=1, D=2 for MT=4) -> D x NI loads in flight per wave.
//   * per-lane GLOBAL addr pre-swizzled (slice ^= row&(S-1)); LDS dest
//     linear (HW: wave-uniform base + lane*16). Read side ds_read_b128 at
//     byte = row*CIN*2 + (slice^(row&(S-1)))*16 — the m214-proven
//     conflict fix for 128B-row tiles.
//   * uniform s_waitcnt vmcnt((D-1)*NI) via dummy tail stages; vmcnt(0) +
//     barrier before the red-reduce phase (stage buffers ALIAS red -> LDS
//     stays 36.3KB, 4 blocks/CU). sched_barrier(0) fences pin the pipeline.
// Everything else (stem/prologue/bnres/launches) byte-identical to r14
// (315.8 us, absmax 0.109375). absmax must be IDENTICAL (same arithmetic).
// ---------------------------------------------------------------------------

typedef float f4 __attribute__((ext_vector_type(4)));
typedef short short8 __attribute__((ext_vector_type(8)));
typedef short short4v __attribute__((ext_vector_type(4)));

#define BN_EPS 1e-5f

static inline int ceil_div(int a, int b) { return (a + b - 1) / b; }

static __device__ inline float btof(short s) {
    unsigned u = ((unsigned)(unsigned short)s) << 16;
    float f;
    __builtin_memcpy(&f, &u, 4);
    return f;
}
static __device__ inline short ftob(float f) {
    __hip_bfloat16 h = __float2bfloat16(f);
    short s;
    __builtin_memcpy(&s, &h, 2);
    return s;
}

// async 16B global->LDS (per-lane global addr; wave-uniform LDS base)
static __device__ inline void gl_lds16(const void* g, void* l) {
    __builtin_amdgcn_global_load_lds(
        (const __attribute__((address_space(1))) void*)g,
        (__attribute__((address_space(3))) void*)l, 16, 0, 0);
}

template <int N>
static __device__ inline void s_wait_vmcnt() {
    static_assert(N >= 0 && N <= 8, "vmcnt range");
    if constexpr (N == 0) asm volatile("s_waitcnt vmcnt(0)" ::: "memory");
    else if constexpr (N == 1) asm volatile("s_waitcnt vmcnt(1)" ::: "memory");
    else if constexpr (N == 2) asm volatile("s_waitcnt vmcnt(2)" ::: "memory");
    else if constexpr (N == 3) asm volatile("s_waitcnt vmcnt(3)" ::: "memory");
    else if constexpr (N == 4) asm volatile("s_waitcnt vmcnt(4)" ::: "memory");
    else if constexpr (N == 5) asm volatile("s_waitcnt vmcnt(5)" ::: "memory");
    else if constexpr (N == 6) asm volatile("s_waitcnt vmcnt(6)" ::: "memory");
    else if constexpr (N == 7) asm volatile("s_waitcnt vmcnt(7)" ::: "memory");
    else asm volatile("s_waitcnt vmcnt(8)" ::: "memory");
}

struct Seg {
    const float* W;
    long long begin, end;
    int K, CIN, COUT;
};

struct ProArgs {
    Seg s[10];
    const float* geo;
    const float* col;
    __hip_bfloat16* x0;
    int n_vox;
    float* stats;
    __hip_bfloat16* pads[5];
    int padn[5];
    long long wf_total;
    long long pro_total;
    __hip_bfloat16* Wf;
    const int* m1;
    __hip_bfloat16* A;
    int nc2;
};

// ---------------- BN coefficient helper ----------------
template <int C>
__device__ inline void bn_coef(const float* st, const float* g, const float* b,
                               int c, int n, float& sc, float& sh) {
    float rn = 1.f / (float)n;
    float sum = st[c] + st[2 * C + c] + st[4 * C + c] + st[6 * C + c];
    float sq  = st[C + c] + st[3 * C + c] + st[5 * C + c] + st[7 * C + c];
    float mu = sum * rn;
    float inv = rsqrtf(sq * rn - mu * mu + BN_EPS);
    sc = inv * g[c];
    sh = b[c] - mu * sc;
}

// ---------------- prologue: pack weights + build x0 + zero stats/pads -------
__global__ __launch_bounds__(256) void k_prologue(ProArgs pa) {
    for (long long e = (long long)blockIdx.x * 256 + threadIdx.x; e < pa.pro_total;
         e += (long long)gridDim.x * 256) {
        if (e < pa.wf_total) {
            int si = 0;
#pragma unroll
            for (int i = 0; i < 10; ++i)
                if (e >= pa.s[i].end) si = i + 1;
            const Seg sg = pa.s[si];
            long long r = e - sg.begin;
            int j = (int)(r & 7);
            int lane = (int)((r >> 3) & 63);
            long long rest = r >> 9;
            int NT = sg.COUT >> 4;
            int ntile = (int)(rest % NT);
            int chunk = (int)(rest / NT);
            int kd = chunk * 32 + ((lane >> 4) << 3) + j;
            int koff = kd / sg.CIN;
            int ci = kd % sg.CIN;
            int n = ntile * 16 + (lane & 15);
            float v = (koff < sg.K) ? sg.W[((size_t)koff * sg.CIN + ci) * sg.COUT + n] : 0.f;
            pa.Wf[e] = __float2bfloat16(v);
            continue;
        }
        long long r = e - pa.wf_total;
        if (r < pa.n_vox) {
            int row = (int)r;
            pa.x0[row * 4 + 0] = __float2bfloat16(pa.geo[row]);
            pa.x0[row * 4 + 1] = __float2bfloat16(pa.col[row * 3 + 0]);
            pa.x0[row * 4 + 2] = __float2bfloat16(pa.col[row * 3 + 1]);
            pa.x0[row * 4 + 3] = __float2bfloat16(pa.col[row * 3 + 2]);
            continue;
        }
        r -= pa.n_vox;
        if (r < 4096) {
            pa.stats[r] = 0.f;
            continue;
        }
        r -= 4096;
#pragma unroll
        for (int i = 0; i < 5; ++i) {
            if (r < pa.padn[i]) {
                pa.pads[i][r] = __float2bfloat16(0.f);
                r = -1;
                break;
            }
            r -= pa.padn[i];
        }
    }
}

// ---------------- stem conv (CIN=4, COUT=32, K=125->128, relu) --------------
__global__ __launch_bounds__(256) void k_stem(ProArgs a) {
    const int t = threadIdx.x, w = t >> 6, lane = t & 63;
    const int quad = lane >> 4, ml = lane & 15;
    const int ntile = w & 1, mgroup = w >> 1;
    const int n_out = a.nc2, n_in = a.n_vox;
    const __hip_bfloat16* feat = a.x0;
    const __hip_bfloat16* Wf = a.Wf;   // stem at offset 0
    const int* in_map = a.m1;
    __hip_bfloat16* out = a.A;
    const int mb = blockIdx.x * 64 + mgroup * 32;
    const int m0 = mb + ml, m1 = mb + 16 + ml;
    const bool v0 = m0 < n_out, v1 = m1 < n_out;
    f4 acc0 = {0.f, 0.f, 0.f, 0.f};
    f4 acc1 = {0.f, 0.f, 0.f, 0.f};
#pragma unroll 2
    for (int chunk = 0; chunk < 16; ++chunk) {
        int k0 = chunk * 8 + quad * 2;
        int k1 = k0 + 1;
        int k0c = (k0 < 125) ? k0 : 0;   // weights zero for k>=125
        int k1c = (k1 < 125) ? k1 : 0;
        short8 b = *(const short8*)(Wf + ((size_t)(chunk * 2 + ntile) * 64 + lane) * 8);
        int ia = v0 ? in_map[(size_t)k0c * n_out + m0] : n_in;
        int ib = v0 ? in_map[(size_t)k1c * n_out + m0] : n_in;
        int ic = v1 ? in_map[(size_t)k0c * n_out + m1] : n_in;
        int id = v1 ? in_map[(size_t)k1c * n_out + m1] : n_in;
        short4v p0 = *(const short4v*)(feat + (size_t)ia * 4);
        short4v p1 = *(const short4v*)(feat + (size_t)ib * 4);
        short4v p2 = *(const short4v*)(feat + (size_t)ic * 4);
        short4v p3 = *(const short4v*)(feat + (size_t)id * 4);
        short8 a0, a1;
        a0[0] = p0[0]; a0[1] = p0[1]; a0[2] = p0[2]; a0[3] = p0[3];
        a0[4] = p1[0]; a0[5] = p1[1]; a0[6] = p1[2]; a0[7] = p1[3];
        a1[0] = p2[0]; a1[1] = p2[1]; a1[2] = p2[2]; a1[3] = p2[3];
        a1[4] = p3[0]; a1[5] = p3[1]; a1[6] = p3[2]; a1[7] = p3[3];
        acc0 = __builtin_amdgcn_mfma_f32_16x16x32_bf16(a0, b, acc0, 0, 0, 0);
        acc1 = __builtin_amdgcn_mfma_f32_16x16x32_bf16(a1, b, acc1, 0, 0, 0);
    }
    const int col = ntile * 16 + ml;
#pragma unroll
    for (int i = 0; i < 4; ++i) {
        int r0 = mb + quad * 4 + i;
        if (r0 < n_out)
            out[(size_t)r0 * 32 + col] = __float2bfloat16(fmaxf(acc0[i], 0.f));
        int r1 = mb + 16 + quad * 4 + i;
        if (r1 < n_out)
            out[(size_t)r1 * 32 + col] = __float2bfloat16(fmaxf(acc1[i], 0.f));
    }
}

// ---------------- split-K MFMA conv, async-LDS-staged gathers ---------------
// Block = 4 waves over R=MT*16 rows; wave w handles taps k=4*kk+w (padded,
// zero weights for k>=K). Gathers staged depth-D via global_load_lds with
// source-swizzled slices; consumed via swizzled ds_read_b128. Stage buffers
// alias the red reduce buffer (disjoint phases, vmcnt(0)+barrier between).
template <int CIN, int COUT, int MT, int K, bool BNF>
__global__ __launch_bounds__(256, 4) void k_conv(
    const __hip_bfloat16* __restrict__ feat,
    const __hip_bfloat16* __restrict__ Wf,
    const int* __restrict__ in_map,
    __hip_bfloat16* __restrict__ out,
    float* __restrict__ stats,
    const float* __restrict__ in_stats,
    const float* __restrict__ in_g,
    const float* __restrict__ in_b,
    int n_out, int n_in) {
    constexpr int NT = COUT / 16;
    constexpr int H = CIN / 32;
    constexpr int R = MT * 16;
    constexpr int KPW = (K + 3) / 4;
    constexpr int SP = COUT + 1;
    constexpr int S = CIN / 8;             // 16B slices per feature row
    constexpr int RPI = 64 / S;            // rows per gload instr (1KB each)
    constexpr int NI = R / RPI;            // gload instrs per stage
    constexpr int D = (MT == 1) ? 4 : 2;   // pipeline depth
    constexpr int STAGE_B = R * CIN * 2;   // stage bytes per wave
    constexpr int STAGE_TOT = 4 * D * STAGE_B;
    constexpr int RED_B = 4 * R * SP * 4;
    constexpr int UNION_B = (STAGE_TOT > RED_B) ? STAGE_TOT : RED_B;
    constexpr int WAIT_N = (D - 1) * NI;   // enc1:4  enc2:6  conv2:3

    __shared__ char smem[UNION_B + 2048 + 512];
    float* red  = (float*)smem;                     // aliases stage region
    float* sred = (float*)(smem + UNION_B);
    float* ibn  = (float*)(smem + UNION_B + 2048);

    const int t = threadIdx.x, w = t >> 6, lane = t & 63;
    const int quad = lane >> 4, ml = lane & 15;
    const int mb = blockIdx.x * R;
    char* stw = smem + w * (D * STAGE_B);           // this wave's stage base
    const int srow = lane / S;                      // staging row-in-instr
    const int ssl = lane & (S - 1);                 // staging physical slice

    if constexpr (BNF) {
        if (t < CIN) {
            float sc, sh;
            bn_coef<CIN>(in_stats, in_g, in_b, t, n_in, sc, sh);
            ibn[t] = sc;
            ibn[CIN + t] = sh;
        }
        __syncthreads();
    }
    float scr[H][8], shr[H][8];
    if constexpr (BNF) {
#pragma unroll
        for (int h = 0; h < H; ++h)
#pragma unroll
            for (int j = 0; j < 8; ++j) {
                int ch = h * 32 + quad * 8 + j;
                scr[h][j] = ibn[ch];
                shr[h][j] = ibn[CIN + ch];
            }
    }

    // ---- per-lane staging indices: idxs[kk][inst] = row (inst*RPI+srow) ----
    int idxs[KPW][NI];
#pragma unroll
    for (int kk = 0; kk < KPW; ++kk) {
        const int k = kk * 4 + w;
        const int krow = (k < K) ? k : 0;     // branchless; weights zero k>=K
        const int* mk = in_map + (size_t)krow * n_out;
#pragma unroll
        for (int inst = 0; inst < NI; ++inst) {
            int m = mb + inst * RPI + srow;
            idxs[kk][inst] = (m < n_out) ? mk[m] : n_in;
        }
    }

    f4 acc[MT * NT];
#pragma unroll
    for (int i = 0; i < MT * NT; ++i) acc[i] = (f4){0.f, 0.f, 0.f, 0.f};

    auto issue = [&](int stg, int slot) {
#pragma unroll
        for (int inst = 0; inst < NI; ++inst) {
            int rg = inst * RPI + srow;
            int gsl = ssl ^ (rg & (S - 1));    // source-swizzled slice
            const __hip_bfloat16* src =
                feat + (size_t)idxs[stg][inst] * CIN + gsl * 8;
            gl_lds16(src, stw + slot * STAGE_B + inst * 1024);
        }
    };

    // ---- pipeline prologue: stages 0..D-1 in flight ----
#pragma unroll
    for (int s = 0; s < D; ++s) issue(s, s);      // KPW(7) > D always

#pragma unroll
    for (int kk = 0; kk < KPW; ++kk) {
        s_wait_vmcnt<WAIT_N>();                    // stage kk landed in LDS
        __builtin_amdgcn_sched_barrier(0);
        const int k = kk * 4 + w;
        const int slot = kk % D;

        short8 bfrag[H * NT];
#pragma unroll
        for (int h = 0; h < H; ++h)
#pragma unroll
            for (int nt = 0; nt < NT; ++nt)
                bfrag[h * NT + nt] = *(const short8*)(
                    Wf + (((size_t)(k * H + h) * NT + nt) * 64 + lane) * 8);

        int cidx[MT];
        if constexpr (BNF) {
            const int krow = (k < K) ? k : 0;
            const int* mk = in_map + (size_t)krow * n_out;
#pragma unroll
            for (int mi = 0; mi < MT; ++mi) {
                int m = mb + mi * 16 + ml;
                cidx[mi] = (m < n_out) ? mk[m] : n_in;
            }
        }

#pragma unroll
        for (int mi = 0; mi < MT; ++mi) {
#pragma unroll
            for (int h = 0; h < H; ++h) {
                const int p = (h * 4 + quad) ^ (ml & (S - 1));
                short8 a = *(const short8*)(
                    stw + slot * STAGE_B + ((mi * 16 + ml) * CIN + p * 8) * 2);
                if constexpr (BNF) {
                    const bool sent = (cidx[mi] == n_in);
#pragma unroll
                    for (int j = 0; j < 8; ++j) {
                        float f = btof(a[j]) * scr[h][j] + shr[h][j];
                        f = fmaxf(f, 0.f);
                        a[j] = sent ? (short)0 : ftob(f);
                    }
                }
#pragma unroll
                for (int nt = 0; nt < NT; ++nt)
                    acc[mi * NT + nt] = __builtin_amdgcn_mfma_f32_16x16x32_bf16(
                        a, bfrag[h * NT + nt], acc[mi * NT + nt], 0, 0, 0);
            }
        }

        // refill the consumed slot (dummy stage keeps vmcnt bookkeeping
        // uniform at the tail; dummies are never read)
        __builtin_amdgcn_sched_barrier(0);
        issue((kk + D < KPW) ? (kk + D) : 0, slot);
    }

    s_wait_vmcnt<0>();      // all staged loads landed; stage region now dead
    __syncthreads();        // all waves done gathering before red alias use

#pragma unroll
    for (int mi = 0; mi < MT; ++mi)
#pragma unroll
        for (int nt = 0; nt < NT; ++nt)
#pragma unroll
            for (int i = 0; i < 4; ++i)
                red[((size_t)w * R + mi * 16 + quad * 4 + i) * SP + nt * 16 + ml] =
                    acc[mi * NT + nt][i];
    __syncthreads();

    constexpr int E = (R * COUT) / 256;
    constexpr int RSTEP = 256 / COUT;
    const int col = t % COUT;
    const int rg = t / COUT;
    float s = 0.f, s2 = 0.f;
#pragma unroll
    for (int i = 0; i < E; ++i) {
        int r = rg + i * RSTEP;
        float v = red[(0 * R + r) * SP + col] + red[(1 * R + r) * SP + col] +
                  red[(2 * R + r) * SP + col] + red[(3 * R + r) * SP + col];
        s += v;
        s2 += v * v;
        int grow = mb + r;
        if (grow < n_out) out[(size_t)grow * COUT + col] = __float2bfloat16(v);
    }

    if (stats) {
        sred[t] = s;
        sred[256 + t] = s2;
        __syncthreads();
        if (t < 2 * COUT) {
            int c = t % COUT;
            int which = t / COUT;   // 0 = sum, 1 = sumsq
            float v = 0.f;
#pragma unroll
            for (int j = 0; j < RSTEP; ++j) v += sred[which * 256 + j * COUT + c];
            atomicAdd(&stats[((blockIdx.x & 3) * 2 + which) * COUT + c], v);
        }
    }
}

// ---------------- BN residual apply ----------------
template <int C, bool F32OUT>
__global__ __launch_bounds__(256) void k_bnres(
    const __hip_bfloat16* __restrict__ y, const __hip_bfloat16* __restrict__ res,
    const float* __restrict__ st, const float* __restrict__ g,
    const float* __restrict__ b, void* outp, int n) {
    __shared__ float ibn[2 * C];
    const int t = threadIdx.x;
    if (t < C) {
        float sc, sh;
        bn_coef<C>(st, g, b, t, n, sc, sh);
        ibn[t] = sc;
        ibn[C + t] = sh;
    }
    __syncthreads();
    long long tot = (long long)n * (C / 8);
    long long i = (long long)blockIdx.x * 256 + t;
    if (i >= tot) return;
    int c0 = (int)(i % (C / 8)) * 8;
    short8 v = *(const short8*)(y + i * 8);
    short8 r = *(const short8*)(res + i * 8);
    if constexpr (F32OUT) {
        float* out = (float*)outp;
        f4 o0, o1;
#pragma unroll
        for (int j = 0; j < 8; ++j) {
            float f = btof(v[j]) * ibn[c0 + j] + ibn[C + c0 + j] + btof(r[j]);
            f = fmaxf(f, 0.f);
            if (j < 4) o0[j] = f; else o1[j - 4] = f;
        }
        *(f4*)(out + i * 8) = o0;
        *(f4*)(out + i * 8 + 4) = o1;
    } else {
        __hip_bfloat16* out = (__hip_bfloat16*)outp;
        short8 o;
#pragma unroll
        for (int j = 0; j < 8; ++j) {
            float f = btof(v[j]) * ibn[c0 + j] + ibn[C + c0 + j] + btof(r[j]);
            o[j] = ftob(fmaxf(f, 0.f));
        }
        *(short8*)(out + i * 8) = o;
    }
}

// ---------------------------------------------------------------------------
extern "C" void kernel_launch(void* const* d_in, const int* in_sizes, int n_in_cnt,
                              void* d_out, int out_size, void* d_ws, size_t ws_size,
                              hipStream_t stream) {
    const float* x_geo = (const float*)d_in[0];
    const float* x_col = (const float*)d_in[1];
    const float* w0    = (const float*)d_in[2];
    const float* w_e1  = (const float*)d_in[3];
    const float* g_e1  = (const float*)d_in[4];
    const float* b_e1  = (const float*)d_in[5];
    const float* w2    = (const float*)d_in[6];
    const float* w_e2  = (const float*)d_in[7];
    const float* g_e2  = (const float*)d_in[8];
    const float* b_e2  = (const float*)d_in[9];
    const int* m1 = (const int*)d_in[10];
    const int* m2 = (const int*)d_in[12];
    const int* m3 = (const int*)d_in[14];
    const int* m4 = (const int*)d_in[16];

    const int n_vox = in_sizes[0];
    const int nc2 = in_sizes[10] / 125;
    const int nc4 = in_sizes[14] / 27;
    (void)out_size; (void)ws_size; (void)n_in_cnt;

    char* p = (char*)d_ws;
    auto alloc = [&](size_t bytes) -> char* {
        char* r = p;
        p += (bytes + 255) & ~(size_t)255;
        return r;
    };
    float* stats = (float*)alloc(8 * 512 * sizeof(float));
    __hip_bfloat16* x0 = (__hip_bfloat16*)alloc((size_t)(n_vox + 1) * 4 * 2);
    __hip_bfloat16* A  = (__hip_bfloat16*)alloc((size_t)(nc2 + 1) * 32 * 2);
    __hip_bfloat16* B  = (__hip_bfloat16*)alloc((size_t)(nc2 + 1) * 32 * 2);
    __hip_bfloat16* Cb = (__hip_bfloat16*)alloc((size_t)(nc2 + 1) * 32 * 2);
    __hip_bfloat16* D  = (__hip_bfloat16*)alloc((size_t)(nc4 + 1) * 64 * 2);
    __hip_bfloat16* E  = (__hip_bfloat16*)alloc((size_t)(nc4 + 1) * 64 * 2);
    __hip_bfloat16* Fb = (__hip_bfloat16*)alloc((size_t)(nc4 + 1) * 64 * 2);

    const long long sz_stem = 16LL * 2 * 512;
    const long long sz_e1   = 28LL * 2 * 512;
    const long long sz_c2   = 28LL * 4 * 512;
    const long long sz_e2   = 56LL * 4 * 512;
    const long long wf_total = sz_stem + 4 * sz_e1 + sz_c2 + 4 * sz_e2;
    __hip_bfloat16* Wf = (__hip_bfloat16*)alloc((size_t)wf_total * 2);

    ProArgs pa;
    long long cur = 0;
    auto seg = [&](int i, const float* W, int K, int CIN, int COUT, long long n) {
        pa.s[i].W = W; pa.s[i].K = K; pa.s[i].CIN = CIN; pa.s[i].COUT = COUT;
        pa.s[i].begin = cur; pa.s[i].end = cur + n; cur += n;
    };
    seg(0, w0, 125, 4, 32, sz_stem);
    for (int i = 0; i < 4; ++i)
        seg(1 + i, w_e1 + (size_t)i * 27 * 32 * 32, 27, 32, 32, sz_e1);
    seg(5, w2, 27, 32, 64, sz_c2);
    for (int i = 0; i < 4; ++i)
        seg(6 + i, w_e2 + (size_t)i * 27 * 64 * 64, 27, 64, 64, sz_e2);

    long long off_e1[4], off_e2[4];
    cur = sz_stem;
    for (int i = 0; i < 4; ++i) { off_e1[i] = cur; cur += sz_e1; }
    long long off_c2 = cur; cur += sz_c2;
    for (int i = 0; i < 4; ++i) { off_e2[i] = cur; cur += sz_e2; }

    pa.geo = x_geo; pa.col = x_col; pa.x0 = x0; pa.n_vox = n_vox;
    pa.stats = stats;
    pa.pads[0] = x0 + (size_t)n_vox * 4; pa.padn[0] = 4;
    pa.pads[1] = A + (size_t)nc2 * 32;   pa.padn[1] = 32;
    pa.pads[2] = B + (size_t)nc2 * 32;   pa.padn[2] = 32;
    pa.pads[3] = D + (size_t)nc4 * 64;   pa.padn[3] = 64;
    pa.pads[4] = E + (size_t)nc4 * 64;   pa.padn[4] = 64;
    pa.wf_total = wf_total;
    pa.pro_total = wf_total + n_vox + 4096 + (4 + 32 + 32 + 64 + 64);
    pa.Wf = Wf;
    pa.m1 = m1;
    pa.A = A;
    pa.nc2 = nc2;

    k_prologue<<<ceil_div((int)pa.pro_total, 256), 256, 0, stream>>>(pa);
    k_stem<<<ceil_div(nc2, 64), 256, 0, stream>>>(pa);

    // enc1: two BasicBlocks, 32ch on c2 (MT=4: R=64 rows/block, split-K 4)
    k_conv<32, 32, 4, 27, false><<<ceil_div(nc2, 64), 256, 0, stream>>>(
        A, Wf + off_e1[0], m2, B, stats + 0 * 512,
        nullptr, nullptr, nullptr, nc2, nc2);
    k_conv<32, 32, 4, 27, true><<<ceil_div(nc2, 64), 256, 0, stream>>>(
        B, Wf + off_e1[1], m2, Cb, stats + 1 * 512,
        stats + 0 * 512, g_e1 + 0, b_e1 + 0, nc2, nc2);
    k_bnres<32, false><<<ceil_div(nc2 * 4, 256), 256, 0, stream>>>(
        Cb, A, stats + 1 * 512, g_e1 + 32, b_e1 + 32, A, nc2);

    k_conv<32, 32, 4, 27, false><<<ceil_div(nc2, 64), 256, 0, stream>>>(
        A, Wf + off_e1[2], m2, B, stats + 2 * 512,
        nullptr, nullptr, nullptr, nc2, nc2);
    k_conv<32, 32, 4, 27, true><<<ceil_div(nc2, 64), 256, 0, stream>>>(
        B, Wf + off_e1[3], m2, Cb, stats + 3 * 512,
        stats + 2 * 512, g_e1 + 64, b_e1 + 64, nc2, nc2);
    k_bnres<32, false><<<ceil_div(nc2 * 4, 256), 256, 0, stream>>>(
        Cb, A, stats + 3 * 512, g_e1 + 96, b_e1 + 96, A, nc2);

    // conv2: 32ch@c2 -> 64ch@c4 (MT=1)
    k_conv<32, 64, 1, 27, false><<<ceil_div(nc4, 16), 256, 0, stream>>>(
        A, Wf + off_c2, m3, D, nullptr,
        nullptr, nullptr, nullptr, nc4, nc2);

    // enc2: two BasicBlocks, 64ch on c4 (MT=1)
    k_conv<64, 64, 1, 27, false><<<ceil_div(nc4, 16), 256, 0, stream>>>(
        D, Wf + off_e2[0], m4, E, stats + 4 * 512,
        nullptr, nullptr, nullptr, nc4, nc4);
    k_conv<64, 64, 1, 27, true><<<ceil_div(nc4, 16), 256, 0, stream>>>(
        E, Wf + off_e2[1], m4, Fb, stats + 5 * 512,
        stats + 4 * 512, g_e2 + 0, b_e2 + 0, nc4, nc4);
    k_bnres<64, false><<<ceil_div(nc4 * 8, 256), 256, 0, stream>>>(
        Fb, D, stats + 5 * 512, g_e2 + 64, b_e2 + 64, D, nc4);

    k_conv<64, 64, 1, 27, false><<<ceil_div(nc4, 16), 256, 0, stream>>>(
        D, Wf + off_e2[2], m4, E, stats + 6 * 512,
        nullptr, nullptr, nullptr, nc4, nc4);
    k_conv<64, 64, 1, 27, true><<<ceil_div(nc4, 16), 256, 0, stream>>>(
        E, Wf + off_e2[3], m4, Fb, stats + 7 * 512,
        stats + 6 * 512, g_e2 + 128, b_e2 + 128, nc4, nc4);
    k_bnres<64, true><<<ceil_div(nc4 * 8, 256), 256, 0, stream>>>(
        Fb, D, stats + 7 * 512, g_e2 + 192, b_e2 + 192, (float*)d_out, nc4);
}

// Round 10
// 310.400 us; speedup vs baseline: 4.9354x; 1.0410x over previous
//
#include <hip/hip_runtime.h>
#include <hip/hip_bf16.h>

// ---------------------------------------------------------------------------
// Sparse conv backbone, bf16 MFMA, round 20 = r19 with queue-ordered weights.
// r19 post-mortem: absmax matched (staging/swizzle correct) but flat — the
// per-iteration bfrag VGPR loads entered the vmcnt queue AFTER the deep
// gather stages; the compiler's wait on bfrag[kk] drained every older entry
// = the whole pipeline, every iteration (same in-order-queue trap as r15).
// r20 invariant: every wait target must be >= D iterations old, and all
// older queue entries must also be >= D iterations old. Scheme (D=2):
//   per iter kk: vmcnt(NI+2NB) [stage kk landed] -> SBAR -> consume
//   (ds_read swizzled slot kk&1 + MFMA with bf[kk&1]; BNF sentinel via
//   __shfl from preloaded idxs — NO memory ops in consume) -> SBAR ->
//   issue [stage kk+2][bfrag kk+2 -> bf[kk&1]] -> SBAR.
// Dummy tail refills keep vmcnt bookkeeping uniform (kept alive by asm).
// launch_bounds (256,3) for BNF/CIN=64 instantiations (bf dbuf +64 VGPR),
// (256,4) otherwise. Everything else byte-identical to r19 (323 us,
// absmax 0.109375 — must match exactly).
// ---------------------------------------------------------------------------

typedef float f4 __attribute__((ext_vector_type(4)));
typedef short short8 __attribute__((ext_vector_type(8)));
typedef short short4v __attribute__((ext_vector_type(4)));

#define BN_EPS 1e-5f

static inline int ceil_div(int a, int b) { return (a + b - 1) / b; }

static __device__ inline float btof(short s) {
    unsigned u = ((unsigned)(unsigned short)s) << 16;
    float f;
    __builtin_memcpy(&f, &u, 4);
    return f;
}
static __device__ inline short ftob(float f) {
    __hip_bfloat16 h = __float2bfloat16(f);
    short s;
    __builtin_memcpy(&s, &h, 2);
    return s;
}

// async 16B global->LDS (per-lane global addr; wave-uniform LDS base)
static __device__ inline void gl_lds16(const void* g, void* l) {
    __builtin_amdgcn_global_load_lds(
        (const __attribute__((address_space(1))) void*)g,
        (__attribute__((address_space(3))) void*)l, 16, 0, 0);
}

template <int N>
static __device__ inline void s_wait_vmcnt() {
    static_assert(N >= 0 && N <= 20, "vmcnt range");
    if constexpr (N == 0) asm volatile("s_waitcnt vmcnt(0)" ::: "memory");
    else if constexpr (N == 8) asm volatile("s_waitcnt vmcnt(8)" ::: "memory");
    else if constexpr (N == 9) asm volatile("s_waitcnt vmcnt(9)" ::: "memory");
    else if constexpr (N == 18) asm volatile("s_waitcnt vmcnt(18)" ::: "memory");
    else if constexpr (N == 1) asm volatile("s_waitcnt vmcnt(1)" ::: "memory");
    else if constexpr (N == 2) asm volatile("s_waitcnt vmcnt(2)" ::: "memory");
    else if constexpr (N == 3) asm volatile("s_waitcnt vmcnt(3)" ::: "memory");
    else if constexpr (N == 4) asm volatile("s_waitcnt vmcnt(4)" ::: "memory");
    else if constexpr (N == 5) asm volatile("s_waitcnt vmcnt(5)" ::: "memory");
    else if constexpr (N == 6) asm volatile("s_waitcnt vmcnt(6)" ::: "memory");
    else if constexpr (N == 10) asm volatile("s_waitcnt vmcnt(10)" ::: "memory");
    else if constexpr (N == 12) asm volatile("s_waitcnt vmcnt(12)" ::: "memory");
    else asm volatile("s_waitcnt vmcnt(16)" ::: "memory");
}

struct Seg {
    const float* W;
    long long begin, end;
    int K, CIN, COUT;
};

struct ProArgs {
    Seg s[10];
    const float* geo;
    const float* col;
    __hip_bfloat16* x0;
    int n_vox;
    float* stats;
    __hip_bfloat16* pads[5];
    int padn[5];
    long long wf_total;
    long long pro_total;
    __hip_bfloat16* Wf;
    const int* m1;
    __hip_bfloat16* A;
    int nc2;
};

// ---------------- BN coefficient helper ----------------
template <int C>
__device__ inline void bn_coef(const float* st, const float* g, const float* b,
                               int c, int n, float& sc, float& sh) {
    float rn = 1.f / (float)n;
    float sum = st[c] + st[2 * C + c] + st[4 * C + c] + st[6 * C + c];
    float sq  = st[C + c] + st[3 * C + c] + st[5 * C + c] + st[7 * C + c];
    float mu = sum * rn;
    float inv = rsqrtf(sq * rn - mu * mu + BN_EPS);
    sc = inv * g[c];
    sh = b[c] - mu * sc;
}

// ---------------- prologue: pack weights + build x0 + zero stats/pads -------
__global__ __launch_bounds__(256) void k_prologue(ProArgs pa) {
    for (long long e = (long long)blockIdx.x * 256 + threadIdx.x; e < pa.pro_total;
         e += (long long)gridDim.x * 256) {
        if (e < pa.wf_total) {
            int si = 0;
#pragma unroll
            for (int i = 0; i < 10; ++i)
                if (e >= pa.s[i].end) si = i + 1;
            const Seg sg = pa.s[si];
            long long r = e - sg.begin;
            int j = (int)(r & 7);
            int lane = (int)((r >> 3) & 63);
            long long rest = r >> 9;
            int NT = sg.COUT >> 4;
            int ntile = (int)(rest % NT);
            int chunk = (int)(rest / NT);
            int kd = chunk * 32 + ((lane >> 4) << 3) + j;
            int koff = kd / sg.CIN;
            int ci = kd % sg.CIN;
            int n = ntile * 16 + (lane & 15);
            float v = (koff < sg.K) ? sg.W[((size_t)koff * sg.CIN + ci) * sg.COUT + n] : 0.f;
            pa.Wf[e] = __float2bfloat16(v);
            continue;
        }
        long long r = e - pa.wf_total;
        if (r < pa.n_vox) {
            int row = (int)r;
            pa.x0[row * 4 + 0] = __float2bfloat16(pa.geo[row]);
            pa.x0[row * 4 + 1] = __float2bfloat16(pa.col[row * 3 + 0]);
            pa.x0[row * 4 + 2] = __float2bfloat16(pa.col[row * 3 + 1]);
            pa.x0[row * 4 + 3] = __float2bfloat16(pa.col[row * 3 + 2]);
            continue;
        }
        r -= pa.n_vox;
        if (r < 4096) {
            pa.stats[r] = 0.f;
            continue;
        }
        r -= 4096;
#pragma unroll
        for (int i = 0; i < 5; ++i) {
            if (r < pa.padn[i]) {
                pa.pads[i][r] = __float2bfloat16(0.f);
                r = -1;
                break;
            }
            r -= pa.padn[i];
        }
    }
}

// ---------------- stem conv (CIN=4, COUT=32, K=125->128, relu) --------------
__global__ __launch_bounds__(256) void k_stem(ProArgs a) {
    const int t = threadIdx.x, w = t >> 6, lane = t & 63;
    const int quad = lane >> 4, ml = lane & 15;
    const int ntile = w & 1, mgroup = w >> 1;
    const int n_out = a.nc2, n_in = a.n_vox;
    const __hip_bfloat16* feat = a.x0;
    const __hip_bfloat16* Wf = a.Wf;   // stem at offset 0
    const int* in_map = a.m1;
    __hip_bfloat16* out = a.A;
    const int mb = blockIdx.x * 64 + mgroup * 32;
    const int m0 = mb + ml, m1 = mb + 16 + ml;
    const bool v0 = m0 < n_out, v1 = m1 < n_out;
    f4 acc0 = {0.f, 0.f, 0.f, 0.f};
    f4 acc1 = {0.f, 0.f, 0.f, 0.f};
#pragma unroll 2
    for (int chunk = 0; chunk < 16; ++chunk) {
        int k0 = chunk * 8 + quad * 2;
        int k1 = k0 + 1;
        int k0c = (k0 < 125) ? k0 : 0;   // weights zero for k>=125
        int k1c = (k1 < 125) ? k1 : 0;
        short8 b = *(const short8*)(Wf + ((size_t)(chunk * 2 + ntile) * 64 + lane) * 8);
        int ia = v0 ? in_map[(size_t)k0c * n_out + m0] : n_in;
        int ib = v0 ? in_map[(size_t)k1c * n_out + m0] : n_in;
        int ic = v1 ? in_map[(size_t)k0c * n_out + m1] : n_in;
        int id = v1 ? in_map[(size_t)k1c * n_out + m1] : n_in;
        short4v p0 = *(const short4v*)(feat + (size_t)ia * 4);
        short4v p1 = *(const short4v*)(feat + (size_t)ib * 4);
        short4v p2 = *(const short4v*)(feat + (size_t)ic * 4);
        short4v p3 = *(const short4v*)(feat + (size_t)id * 4);
        short8 a0, a1;
        a0[0] = p0[0]; a0[1] = p0[1]; a0[2] = p0[2]; a0[3] = p0[3];
        a0[4] = p1[0]; a0[5] = p1[1]; a0[6] = p1[2]; a0[7] = p1[3];
        a1[0] = p2[0]; a1[1] = p2[1]; a1[2] = p2[2]; a1[3] = p2[3];
        a1[4] = p3[0]; a1[5] = p3[1]; a1[6] = p3[2]; a1[7] = p3[3];
        acc0 = __builtin_amdgcn_mfma_f32_16x16x32_bf16(a0, b, acc0, 0, 0, 0);
        acc1 = __builtin_amdgcn_mfma_f32_16x16x32_bf16(a1, b, acc1, 0, 0, 0);
    }
    const int col = ntile * 16 + ml;
#pragma unroll
    for (int i = 0; i < 4; ++i) {
        int r0 = mb + quad * 4 + i;
        if (r0 < n_out)
            out[(size_t)r0 * 32 + col] = __float2bfloat16(fmaxf(acc0[i], 0.f));
        int r1 = mb + 16 + quad * 4 + i;
        if (r1 < n_out)
            out[(size_t)r1 * 32 + col] = __float2bfloat16(fmaxf(acc1[i], 0.f));
    }
}

// ---------------- split-K MFMA conv, fully queue-ordered D=2 pipeline -------
// Block = 4 waves over R=MT*16 rows; wave w handles taps k=4*kk+w (padded,
// zero weights for k>=K). Gathers AND weights staged depth-2 in strict queue
// order: per iter issue [stage kk+2][bfrag kk+2], consume kk. Explicit
// vmcnt(NI+2NB) covers the DMA->ds_read dependence; the compiler's own wait
// for bfrag[kk] (issued 2 iters ago) drains only >=2-iter-old entries.
// BNF sentinel indices derived via __shfl from preloaded idxs (no memory in
// consume). Stage buffers alias the red reduce buffer.
template <int CIN, int COUT, int MT, int K, bool BNF>
__global__ __launch_bounds__(256, ((CIN == 64) || (BNF && CIN == 64)) ? 3 : 4)
void k_conv(
    const __hip_bfloat16* __restrict__ feat,
    const __hip_bfloat16* __restrict__ Wf,
    const int* __restrict__ in_map,
    __hip_bfloat16* __restrict__ out,
    float* __restrict__ stats,
    const float* __restrict__ in_stats,
    const float* __restrict__ in_g,
    const float* __restrict__ in_b,
    int n_out, int n_in) {
    constexpr int NT = COUT / 16;
    constexpr int H = CIN / 32;
    constexpr int R = MT * 16;
    constexpr int KPW = (K + 3) / 4;
    constexpr int SP = COUT + 1;
    constexpr int S = CIN / 8;             // 16B slices per feature row
    constexpr int RPI = 64 / S;            // rows per gload instr (1KB each)
    constexpr int NI = R / RPI;            // gload instrs per stage
    constexpr int NB = H * NT;             // bfrag 16B loads per stage
    constexpr int D = 2;                   // pipeline depth (gathers+weights)
    constexpr int WAIT_N = NI + 2 * NB;    // enc1:8  enc2:18  conv2:9
    constexpr int STAGE_B = R * CIN * 2;   // stage bytes per wave
    constexpr int STAGE_TOT = 4 * D * STAGE_B;
    constexpr int RED_B = 4 * R * SP * 4;
    constexpr int UNION_B = (STAGE_TOT > RED_B) ? STAGE_TOT : RED_B;

    __shared__ char smem[UNION_B + 2048 + 512];
    float* red  = (float*)smem;                     // aliases stage region
    float* sred = (float*)(smem + UNION_B);
    float* ibn  = (float*)(smem + UNION_B + 2048);

    const int t = threadIdx.x, w = t >> 6, lane = t & 63;
    const int quad = lane >> 4, ml = lane & 15;
    const int mb = blockIdx.x * R;
    char* stw = smem + w * (D * STAGE_B);           // this wave's stage base
    const int srow = lane / S;                      // staging row-in-instr
    const int ssl = lane & (S - 1);                 // staging physical slice

    if constexpr (BNF) {
        if (t < CIN) {
            float sc, sh;
            bn_coef<CIN>(in_stats, in_g, in_b, t, n_in, sc, sh);
            ibn[t] = sc;
            ibn[CIN + t] = sh;
        }
        __syncthreads();
    }
    float scr[H][8], shr[H][8];
    if constexpr (BNF) {
#pragma unroll
        for (int h = 0; h < H; ++h)
#pragma unroll
            for (int j = 0; j < 8; ++j) {
                int ch = h * 32 + quad * 8 + j;
                scr[h][j] = ibn[ch];
                shr[h][j] = ibn[CIN + ch];
            }
    }

    // ---- per-lane staging indices: idxs[kk][inst] = row (inst*RPI+srow) ----
    int idxs[KPW][NI];
#pragma unroll
    for (int kk = 0; kk < KPW; ++kk) {
        const int k = kk * 4 + w;
        const int krow = (k < K) ? k : 0;     // branchless; weights zero k>=K
        const int* mk = in_map + (size_t)krow * n_out;
#pragma unroll
        for (int inst = 0; inst < NI; ++inst) {
            int m = mb + inst * RPI + srow;
            idxs[kk][inst] = (m < n_out) ? mk[m] : n_in;
        }
    }

    f4 acc[MT * NT];
#pragma unroll
    for (int i = 0; i < MT * NT; ++i) acc[i] = (f4){0.f, 0.f, 0.f, 0.f};

    short8 bf0[NB], bf1[NB];

    auto issue_stage = [&](int stg, int slot) {
#pragma unroll
        for (int inst = 0; inst < NI; ++inst) {
            int rg = inst * RPI + srow;
            int gsl = ssl ^ (rg & (S - 1));    // source-swizzled slice
            const __hip_bfloat16* src =
                feat + (size_t)idxs[stg][inst] * CIN + gsl * 8;
            gl_lds16(src, stw + slot * STAGE_B + inst * 1024);
        }
    };
    auto issue_bf = [&](int stg, short8 (&bfc)[NB]) {
        const int k = stg * 4 + w;
#pragma unroll
        for (int h = 0; h < H; ++h)
#pragma unroll
            for (int nt = 0; nt < NT; ++nt)
                bfc[h * NT + nt] = *(const short8*)(
                    Wf + (((size_t)(k * H + h) * NT + nt) * 64 + lane) * 8);
    };

    // ---- prologue: strict stage order S0 B0 S1 B1 ----
    issue_stage(0, 0);
    issue_bf(0, bf0);
    issue_stage(1, 1);
    issue_bf(1, bf1);
    __builtin_amdgcn_sched_barrier(0);

#pragma unroll
    for (int kk = 0; kk < KPW; ++kk) {
        s_wait_vmcnt<WAIT_N>();                // stage kk landed in LDS
        __builtin_amdgcn_sched_barrier(0);

        const int slot = kk & 1;
        short8 (&bfc)[NB] = (kk & 1) ? bf1 : bf0;

        // BNF sentinel rows via cross-lane from idxs (no memory ops here)
        int cidx[MT];
        if constexpr (BNF) {
#pragma unroll
            for (int mi = 0; mi < MT; ++mi) {
                if constexpr (RPI >= 16) {
                    // row = mi*16+ml, inst = mi (compile-time), src lane = ml*S
                    cidx[mi] = __shfl(idxs[kk][(mi * 16) / RPI], ml * S);
                } else {
                    // RPI==8 (CIN=64, MT=1): inst = ml/8, src lane = (ml%8)*8
                    int a0 = __shfl(idxs[kk][0], (ml & 7) * S);
                    int a1 = __shfl(idxs[kk][NI - 1], (ml & 7) * S);
                    cidx[mi] = (ml < 8) ? a0 : a1;
                }
            }
        }

#pragma unroll
        for (int mi = 0; mi < MT; ++mi) {
#pragma unroll
            for (int h = 0; h < H; ++h) {
                const int p = (h * 4 + quad) ^ (ml & (S - 1));
                short8 a = *(const short8*)(
                    stw + slot * STAGE_B + ((mi * 16 + ml) * CIN + p * 8) * 2);
                if constexpr (BNF) {
                    const bool sent = (cidx[mi] == n_in);
#pragma unroll
                    for (int j = 0; j < 8; ++j) {
                        float f = btof(a[j]) * scr[h][j] + shr[h][j];
                        f = fmaxf(f, 0.f);
                        a[j] = sent ? (short)0 : ftob(f);
                    }
                }
#pragma unroll
                for (int nt = 0; nt < NT; ++nt)
                    acc[mi * NT + nt] = __builtin_amdgcn_mfma_f32_16x16x32_bf16(
                        a, bfc[h * NT + nt], acc[mi * NT + nt], 0, 0, 0);
            }
        }

        __builtin_amdgcn_sched_barrier(0);
        // refill slot kk&1 with stage kk+2 (dummy wrap keeps count uniform)
        const int ns = (kk + 2 < KPW) ? (kk + 2) : 0;
        issue_stage(ns, slot);
        if (kk & 1) issue_bf(ns, bf1); else issue_bf(ns, bf0);
        __builtin_amdgcn_sched_barrier(0);
    }

    // keep dummy tail bfrag loads alive (prevent DCE -> uniform vmcnt count)
#pragma unroll
    for (int i = 0; i < NB; ++i) {
        asm volatile("" ::"v"(bf0[i]));
        asm volatile("" ::"v"(bf1[i]));
    }

    s_wait_vmcnt<0>();      // all staged loads landed; stage region now dead
    __syncthreads();        // all waves done gathering before red alias use

#pragma unroll
    for (int mi = 0; mi < MT; ++mi)
#pragma unroll
        for (int nt = 0; nt < NT; ++nt)
#pragma unroll
            for (int i = 0; i < 4; ++i)
                red[((size_t)w * R + mi * 16 + quad * 4 + i) * SP + nt * 16 + ml] =
                    acc[mi * NT + nt][i];
    __syncthreads();

    constexpr int E = (R * COUT) / 256;
    constexpr int RSTEP = 256 / COUT;
    const int col = t % COUT;
    const int rg = t / COUT;
    float s = 0.f, s2 = 0.f;
#pragma unroll
    for (int i = 0; i < E; ++i) {
        int r = rg + i * RSTEP;
        float v = red[(0 * R + r) * SP + col] + red[(1 * R + r) * SP + col] +
                  red[(2 * R + r) * SP + col] + red[(3 * R + r) * SP + col];
        s += v;
        s2 += v * v;
        int grow = mb + r;
        if (grow < n_out) out[(size_t)grow * COUT + col] = __float2bfloat16(v);
    }

    if (stats) {
        sred[t] = s;
        sred[256 + t] = s2;
        __syncthreads();
        if (t < 2 * COUT) {
            int c = t % COUT;
            int which = t / COUT;   // 0 = sum, 1 = sumsq
            float v = 0.f;
#pragma unroll
            for (int j = 0; j < RSTEP; ++j) v += sred[which * 256 + j * COUT + c];
            atomicAdd(&stats[((blockIdx.x & 3) * 2 + which) * COUT + c], v);
        }
    }
}

// ---------------- BN residual apply ----------------
template <int C, bool F32OUT>
__global__ __launch_bounds__(256) void k_bnres(
    const __hip_bfloat16* __restrict__ y, const __hip_bfloat16* __restrict__ res,
    const float* __restrict__ st, const float* __restrict__ g,
    const float* __restrict__ b, void* outp, int n) {
    __shared__ float ibn[2 * C];
    const int t = threadIdx.x;
    if (t < C) {
        float sc, sh;
        bn_coef<C>(st, g, b, t, n, sc, sh);
        ibn[t] = sc;
        ibn[C + t] = sh;
    }
    __syncthreads();
    long long tot = (long long)n * (C / 8);
    long long i = (long long)blockIdx.x * 256 + t;
    if (i >= tot) return;
    int c0 = (int)(i % (C / 8)) * 8;
    short8 v = *(const short8*)(y + i * 8);
    short8 r = *(const short8*)(res + i * 8);
    if constexpr (F32OUT) {
        float* out = (float*)outp;
        f4 o0, o1;
#pragma unroll
        for (int j = 0; j < 8; ++j) {
            float f = btof(v[j]) * ibn[c0 + j] + ibn[C + c0 + j] + btof(r[j]);
            f = fmaxf(f, 0.f);
            if (j < 4) o0[j] = f; else o1[j - 4] = f;
        }
        *(f4*)(out + i * 8) = o0;
        *(f4*)(out + i * 8 + 4) = o1;
    } else {
        __hip_bfloat16* out = (__hip_bfloat16*)outp;
        short8 o;
#pragma unroll
        for (int j = 0; j < 8; ++j) {
            float f = btof(v[j]) * ibn[c0 + j] + ibn[C + c0 + j] + btof(r[j]);
            o[j] = ftob(fmaxf(f, 0.f));
        }
        *(short8*)(out + i * 8) = o;
    }
}

// ---------------------------------------------------------------------------
extern "C" void kernel_launch(void* const* d_in, const int* in_sizes, int n_in_cnt,
                              void* d_out, int out_size, void* d_ws, size_t ws_size,
                              hipStream_t stream) {
    const float* x_geo = (const float*)d_in[0];
    const float* x_col = (const float*)d_in[1];
    const float* w0    = (const float*)d_in[2];
    const float* w_e1  = (const float*)d_in[3];
    const float* g_e1  = (const float*)d_in[4];
    const float* b_e1  = (const float*)d_in[5];
    const float* w2    = (const float*)d_in[6];
    const float* w_e2  = (const float*)d_in[7];
    const float* g_e2  = (const float*)d_in[8];
    const float* b_e2  = (const float*)d_in[9];
    const int* m1 = (const int*)d_in[10];
    const int* m2 = (const int*)d_in[12];
    const int* m3 = (const int*)d_in[14];
    const int* m4 = (const int*)d_in[16];

    const int n_vox = in_sizes[0];
    const int nc2 = in_sizes[10] / 125;
    const int nc4 = in_sizes[14] / 27;
    (void)out_size; (void)ws_size; (void)n_in_cnt;

    char* p = (char*)d_ws;
    auto alloc = [&](size_t bytes) -> char* {
        char* r = p;
        p += (bytes + 255) & ~(size_t)255;
        return r;
    };
    float* stats = (float*)alloc(8 * 512 * sizeof(float));
    __hip_bfloat16* x0 = (__hip_bfloat16*)alloc((size_t)(n_vox + 1) * 4 * 2);
    __hip_bfloat16* A  = (__hip_bfloat16*)alloc((size_t)(nc2 + 1) * 32 * 2);
    __hip_bfloat16* B  = (__hip_bfloat16*)alloc((size_t)(nc2 + 1) * 32 * 2);
    __hip_bfloat16* Cb = (__hip_bfloat16*)alloc((size_t)(nc2 + 1) * 32 * 2);
    __hip_bfloat16* D  = (__hip_bfloat16*)alloc((size_t)(nc4 + 1) * 64 * 2);
    __hip_bfloat16* E  = (__hip_bfloat16*)alloc((size_t)(nc4 + 1) * 64 * 2);
    __hip_bfloat16* Fb = (__hip_bfloat16*)alloc((size_t)(nc4 + 1) * 64 * 2);

    const long long sz_stem = 16LL * 2 * 512;
    const long long sz_e1   = 28LL * 2 * 512;
    const long long sz_c2   = 28LL * 4 * 512;
    const long long sz_e2   = 56LL * 4 * 512;
    const long long wf_total = sz_stem + 4 * sz_e1 + sz_c2 + 4 * sz_e2;
    __hip_bfloat16* Wf = (__hip_bfloat16*)alloc((size_t)wf_total * 2);

    ProArgs pa;
    long long cur = 0;
    auto seg = [&](int i, const float* W, int K, int CIN, int COUT, long long n) {
        pa.s[i].W = W; pa.s[i].K = K; pa.s[i].CIN = CIN; pa.s[i].COUT = COUT;
        pa.s[i].begin = cur; pa.s[i].end = cur + n; cur += n;
    };
    seg(0, w0, 125, 4, 32, sz_stem);
    for (int i = 0; i < 4; ++i)
        seg(1 + i, w_e1 + (size_t)i * 27 * 32 * 32, 27, 32, 32, sz_e1);
    seg(5, w2, 27, 32, 64, sz_c2);
    for (int i = 0; i < 4; ++i)
        seg(6 + i, w_e2 + (size_t)i * 27 * 64 * 64, 27, 64, 64, sz_e2);

    long long off_e1[4], off_e2[4];
    cur = sz_stem;
    for (int i = 0; i < 4; ++i) { off_e1[i] = cur; cur += sz_e1; }
    long long off_c2 = cur; cur += sz_c2;
    for (int i = 0; i < 4; ++i) { off_e2[i] = cur; cur += sz_e2; }

    pa.geo = x_geo; pa.col = x_col; pa.x0 = x0; pa.n_vox = n_vox;
    pa.stats = stats;
    pa.pads[0] = x0 + (size_t)n_vox * 4; pa.padn[0] = 4;
    pa.pads[1] = A + (size_t)nc2 * 32;   pa.padn[1] = 32;
    pa.pads[2] = B + (size_t)nc2 * 32;   pa.padn[2] = 32;
    pa.pads[3] = D + (size_t)nc4 * 64;   pa.padn[3] = 64;
    pa.pads[4] = E + (size_t)nc4 * 64;   pa.padn[4] = 64;
    pa.wf_total = wf_total;
    pa.pro_total = wf_total + n_vox + 4096 + (4 + 32 + 32 + 64 + 64);
    pa.Wf = Wf;
    pa.m1 = m1;
    pa.A = A;
    pa.nc2 = nc2;

    k_prologue<<<ceil_div((int)pa.pro_total, 256), 256, 0, stream>>>(pa);
    k_stem<<<ceil_div(nc2, 64), 256, 0, stream>>>(pa);

    // enc1: two BasicBlocks, 32ch on c2 (MT=4: R=64 rows/block, split-K 4)
    k_conv<32, 32, 4, 27, false><<<ceil_div(nc2, 64), 256, 0, stream>>>(
        A, Wf + off_e1[0], m2, B, stats + 0 * 512,
        nullptr, nullptr, nullptr, nc2, nc2);
    k_conv<32, 32, 4, 27, true><<<ceil_div(nc2, 64), 256, 0, stream>>>(
        B, Wf + off_e1[1], m2, Cb, stats + 1 * 512,
        stats + 0 * 512, g_e1 + 0, b_e1 + 0, nc2, nc2);
    k_bnres<32, false><<<ceil_div(nc2 * 4, 256), 256, 0, stream>>>(
        Cb, A, stats + 1 * 512, g_e1 + 32, b_e1 + 32, A, nc2);

    k_conv<32, 32, 4, 27, false><<<ceil_div(nc2, 64), 256, 0, stream>>>(
        A, Wf + off_e1[2], m2, B, stats + 2 * 512,
        nullptr, nullptr, nullptr, nc2, nc2);
    k_conv<32, 32, 4, 27, true><<<ceil_div(nc2, 64), 256, 0, stream>>>(
        B, Wf + off_e1[3], m2, Cb, stats + 3 * 512,
        stats + 2 * 512, g_e1 + 64, b_e1 + 64, nc2, nc2);
    k_bnres<32, false><<<ceil_div(nc2 * 4, 256), 256, 0, stream>>>(
        Cb, A, stats + 3 * 512, g_e1 + 96, b_e1 + 96, A, nc2);

    // conv2: 32ch@c2 -> 64ch@c4 (MT=1)
    k_conv<32, 64, 1, 27, false><<<ceil_div(nc4, 16), 256, 0, stream>>>(
        A, Wf + off_c2, m3, D, nullptr,
        nullptr, nullptr, nullptr, nc4, nc2);

    // enc2: two BasicBlocks, 64ch on c4 (MT=1)
    k_conv<64, 64, 1, 27, false><<<ceil_div(nc4, 16), 256, 0, stream>>>(
        D, Wf + off_e2[0], m4, E, stats + 4 * 512,
        nullptr, nullptr, nullptr, nc4, nc4);
    k_conv<64, 64, 1, 27, true><<<ceil_div(nc4, 16), 256, 0, stream>>>(
        E, Wf + off_e2[1], m4, Fb, stats + 5 * 512,
        stats + 4 * 512, g_e2 + 0, b_e2 + 0, nc4, nc4);
    k_bnres<64, false><<<ceil_div(nc4 * 8, 256), 256, 0, stream>>>(
        Fb, D, stats + 5 * 512, g_e2 + 64, b_e2 + 64, D, nc4);

    k_conv<64, 64, 1, 27, false><<<ceil_div(nc4, 16), 256, 0, stream>>>(
        D, Wf + off_e2[2], m4, E, stats + 6 * 512,
        nullptr, nullptr, nullptr, nc4, nc4);
    k_conv<64, 64, 1, 27, true><<<ceil_div(nc4, 16), 256, 0, stream>>>(
        E, Wf + off_e2[3], m4, Fb, stats + 7 * 512,
        stats + 6 * 512, g_e2 + 128, b_e2 + 128, nc4, nc4);
    k_bnres<64, true><<<ceil_div(nc4 * 8, 256), 256, 0, stream>>>(
        Fb, D, stats + 7 * 512, g_e2 + 192, b_e2 + 192, (float*)d_out, nc4);
}